// Round 3
// baseline (403.830 us; speedup 1.0000x reference)
//
#include <hip/hip_runtime.h>

// DynamicHead R5 = R4 (ko-outer/s-inner K-loop, (ko,s)-linear B stream,
// triple-buffered B prefetch) + layer1/layer2 fusion (X1 never touches HBM;
// inter-layer handoff is a register->LDS writeback into the same Xl tile).
//   out[m,o] = sum_{s,i} (bas_s[m]*x[m,i]) * W[s,i,o] + sum_s bas_s[m]*b[s,o]
// [R2: resubmission — broker timeout x3, kernel held fixed for attribution]

typedef __attribute__((ext_vector_type(8))) _Float16 half8;
typedef __attribute__((ext_vector_type(4))) _Float16 half4;
typedef __attribute__((ext_vector_type(4))) float floatx4;

#define XPAD 264  // halves per LDS row: 256 + 8

__device__ __forceinline__ void make_basis(float t, float* p){
  p[0] = 1.f; p[1] = t; p[2] = t*t; p[3] = p[2]*t;
  const float knots[8] = {1.f/9.f, 2.f/9.f, 3.f/9.f, 4.f/9.f,
                          5.f/9.f, 6.f/9.f, 7.f/9.f, 8.f/9.f};
  #pragma unroll
  for (int j = 0; j < 8; ++j){
    float d = t - knots[j];
    d = fmaxf(d, 0.f);
    p[4+j] = d*d*d;
  }
}

// Pack W (12,256,256) fp32 -> f16 MFMA-B-frag order via LDS transpose.
// kappa = s*8+ko; destination block position t = ko*12 + s (ko-outer stream
// order so the layer kernel's B pointer advances linearly 8192 halves/kstep).
// One block per (layer, kappa): 192 blocks.
__global__ __launch_bounds__(256)
void pack_w_kernel(const float* __restrict__ W0, const float* __restrict__ W1,
                   _Float16* __restrict__ Wp0, _Float16* __restrict__ Wp1){
  __shared__ float wl[32 * 260];
  const int blk = blockIdx.x;
  const float* W = (blk < 96) ? W0 : W1;
  _Float16* Wp   = (blk < 96) ? Wp0 : Wp1;
  const int c    = (blk < 96) ? blk : blk - 96;   // kappa = s*8+ko
  const int tid  = threadIdx.x;
  const float* src = W + (size_t)c * 8192;        // 32 k-rows x 256 cols
  #pragma unroll
  for (int it = 0; it < 8; ++it){
    int idx = it * 256 + tid;          // float4 index 0..2047
    int r = idx >> 6, c4 = idx & 63;
    float4 v = *(const float4*)(src + (size_t)idx * 4);
    float* d = &wl[r * 260 + c4 * 4];
    d[0] = v.x; d[1] = v.y; d[2] = v.z; d[3] = v.w;
  }
  __syncthreads();
  const int tpos = (c & 7) * 12 + (c >> 3);       // ko*12 + s
  _Float16* dst = Wp + (size_t)tpos * 8192;
  #pragma unroll
  for (int w = 0; w < 4; ++w){
    int v = w * 256 + tid;             // 0..1023
    int n16 = v & 15, qq = (v >> 4) & 3, ntg = v >> 6;
    half8 o;
    #pragma unroll
    for (int j = 0; j < 8; ++j)
      o[j] = (_Float16)wl[(qq * 8 + j) * 260 + ntg * 16 + n16];
    *(half8*)(dst + (size_t)v * 8) = o;
  }
}

// One 96-kstep GEMM pass over the staged Xl tile with the (ko,s)-linear
// B stream. A-frags hoisted out of the s-loop (only re-read per ko);
// B 2-deep prefetch, static 3-buffer rotation (12%3==0).
// NOTE: the 2 tail B-prefetches (t=96,97) overrun <=32KiB past this layer's Wp
// into the next allocated workspace region. Values never consumed -> safe.
__device__ __forceinline__ void gemm_kloop(const _Float16* Xl, const float* bldsT,
                                           const _Float16* __restrict__ wb,
                                           unsigned xbase, int wm, int l16,
                                           floatx4 acc[4][4]){
  half8 xc[4], xn[4];
  half8 b[3][4];                        // triple buffer, index = s % 3 (static)
  #pragma unroll
  for (int mt = 0; mt < 4; ++mt)
    xc[mt] = *(const half8*)&Xl[xbase + mt * 16 * XPAD];
  #pragma unroll
  for (int nt = 0; nt < 4; ++nt){
    b[0][nt] = *(const half8*)(wb + nt * 512);
    b[1][nt] = *(const half8*)(wb + 8192 + nt * 512);
  }
  const _Float16* wpre = wb + 2 * 8192; // points at kstep t+2

  for (int ko = 0; ko < 8; ++ko){
    #pragma unroll
    for (int s = 0; s < 12; ++s){
      // prefetch B for kstep t+2 (buffer index static per s)
      #pragma unroll
      for (int nt = 0; nt < 4; ++nt)
        b[(s + 2) % 3][nt] = *(const half8*)(wpre + nt * 512);
      wpre += 8192;

      if (s == 0){
        // prefetch next ko's A-frags (11 ksteps of latency cover)
        const int kon = (ko + 1) & 7;   // wraps at ko=7; result discarded
        #pragma unroll
        for (int mt = 0; mt < 4; ++mt)
          xn[mt] = *(const half8*)&Xl[xbase + kon * 32 + mt * 16 * XPAD];
      }

      // basis: one broadcast ds_read_b128 -> 4 per-mt scalars
      floatx4 bt = *(const floatx4*)&bldsT[s * 128 + wm * 64 + l16 * 4];
      _Float16 bh[4];
      #pragma unroll
      for (int mt = 0; mt < 4; ++mt) bh[mt] = (_Float16)bt[mt];

      // apply basis to A (v_pk_mul_f16), then MFMA
      half8 az[4];
      #pragma unroll
      for (int mt = 0; mt < 4; ++mt) az[mt] = xc[mt] * bh[mt];
      #pragma unroll
      for (int mt = 0; mt < 4; ++mt)
        #pragma unroll
        for (int nt = 0; nt < 4; ++nt)
          acc[mt][nt] = __builtin_amdgcn_mfma_f32_16x16x32_f16(
              az[mt], b[s % 3][nt], acc[mt][nt], 0, 0, 0);
    }
    #pragma unroll
    for (int mt = 0; mt < 4; ++mt) xc[mt] = xn[mt];
  }
}

// acc[mt][nt] += sum_s bas_s[row] * bias[s, col]
__device__ __forceinline__ void add_bias(const float* blds, const float* __restrict__ bias,
                                         int wm, int wn, int q, int l16,
                                         floatx4 acc[4][4]){
  for (int s = 0; s < 12; ++s){
    float bl[4];
    #pragma unroll
    for (int nt = 0; nt < 4; ++nt)
      bl[nt] = bias[s * 256 + wn * 64 + nt * 16 + l16];
    floatx4 bs[4];
    #pragma unroll
    for (int mt = 0; mt < 4; ++mt)
      bs[mt] = *(const floatx4*)&blds[s * 128 + wm * 64 + mt * 16 + q * 4];
    #pragma unroll
    for (int mt = 0; mt < 4; ++mt)
      #pragma unroll
      for (int nt = 0; nt < 4; ++nt)
        #pragma unroll
        for (int r = 0; r < 4; ++r)
          acc[mt][nt][r] += bs[mt][r] * bl[nt];
  }
}

// Fused layers 1+2: block = 128 rows x 256 cols (full feature dim), so each
// block owns its rows' complete intermediate activation -> X1 stays in LDS.
// 512 threads = 8 waves as 2(m) x 4(n) of 64x64. Grid: 256 blocks, 1/CU.
__global__ __launch_bounds__(512, 2)
void fused_layers_kernel(const float* __restrict__ feat, const float* __restrict__ treat,
                         const _Float16* __restrict__ Wp0, const float* __restrict__ b0,
                         const _Float16* __restrict__ Wp1, const float* __restrict__ b1,
                         _Float16* __restrict__ X2){
  __shared__ _Float16 Xl[128 * XPAD];   // 67,584 B
  __shared__ float blds[12 * 128];      // 6,144 B (epilogue layout)
  __shared__ float bldsT[12 * 128];     // 6,144 B (k-loop layout: [s][wm][l16][mt])

  const int tid  = threadIdx.x;
  const int m0   = blockIdx.x * 128;
  const int lane = tid & 63;
  const int wid  = tid >> 6;
  const int wm   = wid >> 2;            // 0..1: rows wm*64..+64
  const int wn   = wid & 3;             // 0..3: cols wn*64..+64
  const int q    = lane >> 4;
  const int l16  = lane & 15;

  // ---- stage features (128 x 256, f32 -> f16) into LDS ----
  #pragma unroll
  for (int it = 0; it < 16; ++it){
    int idx = it * 512 + tid;            // 8192 float4 chunks
    int m = idx >> 6, c = idx & 63;
    float4 v = *(const float4*)(feat + (size_t)(m0 + m) * 256 + c * 4);
    half4 h = { (_Float16)v.x, (_Float16)v.y, (_Float16)v.z, (_Float16)v.w };
    *(half4*)&Xl[m * XPAD + c * 4] = h;
  }
  if (tid < 128){
    float t = treat[m0 + tid];
    float p[12]; make_basis(t, p);
    const int r   = tid;
    const int tmt = (r >> 4) & 3;        // row's mt index within its wm half
    const int tl  = r & 15;              // row's l16
    const int twm = r >> 6;
    #pragma unroll
    for (int s = 0; s < 12; ++s){
      blds [s * 128 + r] = p[s];
      bldsT[s * 128 + twm * 64 + tl * 4 + tmt] = p[s];
    }
  }
  __syncthreads();

  // A frag: row = wm*64 + mt*16 + l16, k = ko*32 + q*8 + j (halves in Xl)
  const unsigned xbase = (unsigned)(wm * 64 + l16) * XPAD + q * 8;

  const floatx4 zero = {0.f, 0.f, 0.f, 0.f};
  floatx4 acc[4][4];
  #pragma unroll
  for (int mt = 0; mt < 4; ++mt)
    #pragma unroll
    for (int nt = 0; nt < 4; ++nt) acc[mt][nt] = zero;

  // ---- layer 1 ----
  gemm_kloop(Xl, bldsT, Wp0 + wn * 2048 + lane * 8, xbase, wm, l16, acc);
  add_bias(blds, b0, wm, wn, q, l16, acc);

  // relu + write activation back into Xl (all waves done reading layer-1 Xl)
  __syncthreads();
  // C/D layout: col = lane&15, row = (lane>>4)*4 + reg
  #pragma unroll
  for (int mt = 0; mt < 4; ++mt)
    #pragma unroll
    for (int nt = 0; nt < 4; ++nt)
      #pragma unroll
      for (int r = 0; r < 4; ++r)
        Xl[(wm * 64 + mt * 16 + q * 4 + r) * XPAD + wn * 64 + nt * 16 + l16] =
            (_Float16)fmaxf(acc[mt][nt][r], 0.f);
  __syncthreads();

  // ---- layer 2 ----
  #pragma unroll
  for (int mt = 0; mt < 4; ++mt)
    #pragma unroll
    for (int nt = 0; nt < 4; ++nt) acc[mt][nt] = zero;
  gemm_kloop(Xl, bldsT, Wp1 + wn * 2048 + lane * 8, xbase, wm, l16, acc);
  add_bias(blds, b1, wm, wn, q, l16, acc);

  // relu + f16 store of X2
  #pragma unroll
  for (int mt = 0; mt < 4; ++mt){
    #pragma unroll
    for (int nt = 0; nt < 4; ++nt){
      int col = wn * 64 + nt * 16 + l16;
      #pragma unroll
      for (int r = 0; r < 4; ++r){
        int row = m0 + wm * 64 + mt * 16 + q * 4 + r;
        X2[(size_t)row * 256 + col] = (_Float16)fmaxf(acc[mt][nt][r], 0.f);
      }
    }
  }
}

// Final layer (out dim 1): one wave per 4 rows, W2 staged in LDS. 2048 blocks.
__global__ __launch_bounds__(256)
void final_kernel(const _Float16* __restrict__ X2, const float* __restrict__ treat,
                  const float* __restrict__ W2, const float* __restrict__ b2,
                  float* __restrict__ out){
  __shared__ float w2l[12 * 256];
  __shared__ float b2l[12];
  const int tid = threadIdx.x;
  const int m0 = blockIdx.x * 16;
  #pragma unroll
  for (int it = 0; it < 12; ++it) w2l[it * 256 + tid] = W2[it * 256 + tid];
  if (tid < 12) b2l[tid] = b2[tid];
  __syncthreads();
  const int lane = tid & 63, wid = tid >> 6;
  #pragma unroll
  for (int rr = 0; rr < 4; ++rr){
    int b = m0 + wid * 4 + rr;
    float t = treat[b];
    float p[12]; make_basis(t, p);
    half4 xv = *(const half4*)(X2 + (size_t)b * 256 + lane * 4);
    float xs[4] = { (float)xv.x, (float)xv.y, (float)xv.z, (float)xv.w };
    float ws[4] = {0.f, 0.f, 0.f, 0.f};
    #pragma unroll
    for (int s = 0; s < 12; ++s){
      floatx4 w4 = *(const floatx4*)&w2l[s * 256 + lane * 4];
      #pragma unroll
      for (int j = 0; j < 4; ++j) ws[j] += p[s] * w4[j];
    }
    float dot = xs[0]*ws[0] + xs[1]*ws[1] + xs[2]*ws[2] + xs[3]*ws[3];
    #pragma unroll
    for (int off = 32; off > 0; off >>= 1) dot += __shfl_down(dot, off, 64);
    if (lane == 0){
      float bb = 0.f;
      #pragma unroll
      for (int s = 0; s < 12; ++s) bb += p[s] * b2l[s];
      out[b] = dot + bb;
    }
  }
}

extern "C" void kernel_launch(void* const* d_in, const int* in_sizes, int n_in,
                              void* d_out, int out_size, void* d_ws, size_t ws_size,
                              hipStream_t stream){
  const float* treat = (const float*)d_in[0];
  const float* feat  = (const float*)d_in[1];
  const float* W0    = (const float*)d_in[2];
  const float* b0    = (const float*)d_in[3];
  const float* W1    = (const float*)d_in[4];
  const float* b1    = (const float*)d_in[5];
  const float* W2    = (const float*)d_in[6];
  const float* b2    = (const float*)d_in[7];

  char* ws = (char*)d_ws;
  _Float16* Wp0 = (_Float16*)(ws);                     // 1,572,864 B
  _Float16* Wp1 = (_Float16*)(ws + 1572864);           // 1,572,864 B (also Wp0 overrun pad)
  _Float16* X2  = (_Float16*)(ws + 3145728);           // 16,777,216 B (also Wp1 overrun pad)
  float* out = (float*)d_out;

  pack_w_kernel<<<192, 256, 0, stream>>>(W0, W1, Wp0, Wp1);
  fused_layers_kernel<<<256, 512, 0, stream>>>(feat, treat, Wp0, b0, Wp1, b1, X2);
  final_kernel<<<2048, 256, 0, stream>>>(X2, treat, W2, b2, out);
}

// Round 6
// 190.859 us; speedup vs baseline: 2.1159x; 2.1159x over previous
//
#include <hip/hip_runtime.h>

// DynamicHead R6: R5's fusion kept; B-path rebuilt as global_load_lds -> 4-deep
// LDS ring with counted s_waitcnt vmcnt(4) + raw s_barrier per kstep (T3/T4).
// R5 counters: MfmaUtil 13%, FETCH 720MiB (=256 blocks x full Wp, zero L2 dedup)
// -> latency-bound on the B stream; register prefetch couldn't cover ~600-900cy.
// Also: X2 stored via LDS bounce as coalesced half8 (R5 WRITE_SIZE was 12x payload).
// [R5: third submission of this source — broker timeouts; held fixed for attribution]

typedef __attribute__((ext_vector_type(8))) _Float16 half8;
typedef __attribute__((ext_vector_type(4))) _Float16 half4;
typedef __attribute__((ext_vector_type(4))) float floatx4;

#define XPAD 264  // halves per LDS row: 256 + 8

__device__ __forceinline__ void gload16(const _Float16* g, _Float16* l){
  // async global->LDS, 16B/lane; LDS dest = wave-uniform base + lane*16
  __builtin_amdgcn_global_load_lds(
      (const __attribute__((address_space(1))) void*)g,
      (__attribute__((address_space(3))) void*)l, 16, 0, 0);
}

// Stage one 16KB kstep-block of packed W into an LDS slot (2 chunks/thread).
// Layout is linear: byte i of the block -> slot byte i (lanes consume it so).
__device__ __forceinline__ void stage_b(const _Float16* wt, _Float16* slot,
                                        int w, int l){
  gload16(wt +        w * 512 + l * 8, slot +        w * 512);
  gload16(wt + 4096 + w * 512 + l * 8, slot + 4096 + w * 512);
}

__device__ __forceinline__ void make_basis(float t, float* p){
  p[0] = 1.f; p[1] = t; p[2] = t*t; p[3] = p[2]*t;
  const float knots[8] = {1.f/9.f, 2.f/9.f, 3.f/9.f, 4.f/9.f,
                          5.f/9.f, 6.f/9.f, 7.f/9.f, 8.f/9.f};
  #pragma unroll
  for (int j = 0; j < 8; ++j){
    float d = t - knots[j];
    d = fmaxf(d, 0.f);
    p[4+j] = d*d*d;
  }
}

// Pack W (12,256,256) fp32 -> f16 MFMA-B-frag order via LDS transpose.
// kappa = s*8+ko; destination block position t = ko*12 + s (ko-outer stream
// order so the layer kernel's B pointer advances linearly 8192 halves/kstep).
__global__ __launch_bounds__(256)
void pack_w_kernel(const float* __restrict__ W0, const float* __restrict__ W1,
                   _Float16* __restrict__ Wp0, _Float16* __restrict__ Wp1){
  __shared__ float wl[32 * 260];
  const int blk = blockIdx.x;
  const float* W = (blk < 96) ? W0 : W1;
  _Float16* Wp   = (blk < 96) ? Wp0 : Wp1;
  const int c    = (blk < 96) ? blk : blk - 96;   // kappa = s*8+ko
  const int tid  = threadIdx.x;
  const float* src = W + (size_t)c * 8192;        // 32 k-rows x 256 cols
  #pragma unroll
  for (int it = 0; it < 8; ++it){
    int idx = it * 256 + tid;          // float4 index 0..2047
    int r = idx >> 6, c4 = idx & 63;
    float4 v = *(const float4*)(src + (size_t)idx * 4);
    float* d = &wl[r * 260 + c4 * 4];
    d[0] = v.x; d[1] = v.y; d[2] = v.z; d[3] = v.w;
  }
  __syncthreads();
  const int tpos = (c & 7) * 12 + (c >> 3);       // ko*12 + s
  _Float16* dst = Wp + (size_t)tpos * 8192;
  #pragma unroll
  for (int w = 0; w < 4; ++w){
    int v = w * 256 + tid;             // 0..1023
    int n16 = v & 15, qq = (v >> 4) & 3, ntg = v >> 6;
    half8 o;
    #pragma unroll
    for (int j = 0; j < 8; ++j)
      o[j] = (_Float16)wl[(qq * 8 + j) * 260 + ntg * 16 + n16];
    *(half8*)(dst + (size_t)v * 8) = o;
  }
}

// 96-kstep GEMM pass. B flows global->LDS ring (4 slots x 16KB), issue
// distance 2, vmcnt(4) = 2 loads/iter x 2 iters in flight; one raw s_barrier
// per kstep (reads of slot t end before barrier(t); its overwrite is issued
// after barrier(t+1) -> safe). Slot indices static since 12 % 4 == 0.
// Caller must pre-stage t=0,1 into slots 0,1 and __syncthreads (drain).
// Tail stages t=96,97 overrun <=32KiB into the next allocated ws region.
__device__ __forceinline__ void gemm_kloop(const _Float16* Xl, _Float16* Bl,
                                           const float* bldsT,
                                           const _Float16* __restrict__ wp,
                                           unsigned xbase, int wm, int wn,
                                           int l16, int w, int l,
                                           floatx4 acc[4][4]){
  const unsigned bbase = (unsigned)(wn * 2048 + l * 8);   // halves within slot
  half8 xc[4];
  for (int ko = 0; ko < 8; ++ko){
    #pragma unroll
    for (int s = 0; s < 12; ++s){
      // issue B loads for kstep t+2
      stage_b(wp + (size_t)(ko * 12 + s + 2) * 8192,
              Bl + ((s + 2) & 3) * 8192, w, l);
      // own loads for kstep t are done once <=4 remain in flight
      __asm__ __volatile__("s_waitcnt vmcnt(4)" ::: "memory");
      __builtin_amdgcn_sched_barrier(0);
      __builtin_amdgcn_s_barrier();   // all waves' t-loads landed
      __builtin_amdgcn_sched_barrier(0);

      if (s == 0){   // A-frags for this ko (reused for 12 ksteps)
        #pragma unroll
        for (int mt = 0; mt < 4; ++mt)
          xc[mt] = *(const half8*)&Xl[xbase + ko * 32 + mt * 16 * XPAD];
      }
      // basis: one broadcast ds_read_b128 -> 4 per-mt scalars
      floatx4 bt = *(const floatx4*)&bldsT[s * 128 + wm * 64 + l16 * 4];
      _Float16 bh[4];
      #pragma unroll
      for (int mt = 0; mt < 4; ++mt) bh[mt] = (_Float16)bt[mt];
      half8 az[4];
      #pragma unroll
      for (int mt = 0; mt < 4; ++mt) az[mt] = xc[mt] * bh[mt];

      const _Float16* bslot = Bl + (s & 3) * 8192 + bbase;
      half8 bf[4];
      #pragma unroll
      for (int nt = 0; nt < 4; ++nt)
        bf[nt] = *(const half8*)(bslot + nt * 512);
      #pragma unroll
      for (int mt = 0; mt < 4; ++mt)
        #pragma unroll
        for (int nt = 0; nt < 4; ++nt)
          acc[mt][nt] = __builtin_amdgcn_mfma_f32_16x16x32_f16(
              az[mt], bf[nt], acc[mt][nt], 0, 0, 0);
    }
  }
}

// acc[mt][nt] += sum_s bas_s[row] * bias[s, col]
__device__ __forceinline__ void add_bias(const float* blds, const float* __restrict__ bias,
                                         int wm, int wn, int q, int l16,
                                         floatx4 acc[4][4]){
  for (int s = 0; s < 12; ++s){
    float bl[4];
    #pragma unroll
    for (int nt = 0; nt < 4; ++nt)
      bl[nt] = bias[s * 256 + wn * 64 + nt * 16 + l16];
    floatx4 bs[4];
    #pragma unroll
    for (int mt = 0; mt < 4; ++mt)
      bs[mt] = *(const floatx4*)&blds[s * 128 + wm * 64 + mt * 16 + q * 4];
    #pragma unroll
    for (int mt = 0; mt < 4; ++mt)
      #pragma unroll
      for (int nt = 0; nt < 4; ++nt)
        #pragma unroll
        for (int r = 0; r < 4; ++r)
          acc[mt][nt][r] += bs[mt][r] * bl[nt];
  }
}

// relu + scatter acc into Xl as f16 (C/D layout: col=lane&15, row=(lane>>4)*4+r)
__device__ __forceinline__ void scatter_to_xl(_Float16* Xl, floatx4 acc[4][4],
                                              int wm, int wn, int q, int l16){
  #pragma unroll
  for (int mt = 0; mt < 4; ++mt)
    #pragma unroll
    for (int nt = 0; nt < 4; ++nt)
      #pragma unroll
      for (int r = 0; r < 4; ++r)
        Xl[(wm * 64 + mt * 16 + q * 4 + r) * XPAD + wn * 64 + nt * 16 + l16] =
            (_Float16)fmaxf(acc[mt][nt][r], 0.f);
}

// Fused layers 1+2: 128 rows x 256 cols per block, 512 thr = 8 waves (2m x 4n).
// Grid 256 -> 1 block/CU. LDS: Xl 67.5K + Bl 64K + basis 12K = 145,408 B.
__global__ __launch_bounds__(512, 2)
void fused_layers_kernel(const float* __restrict__ feat, const float* __restrict__ treat,
                         const _Float16* __restrict__ Wp0, const float* __restrict__ b0,
                         const _Float16* __restrict__ Wp1, const float* __restrict__ b1,
                         _Float16* __restrict__ X2){
  __shared__ _Float16 Xl[128 * XPAD];   // 67,584 B
  __shared__ _Float16 Bl[4 * 8192];     // 65,536 B (B ring)
  __shared__ float blds[12 * 128];      // 6,144 B (epilogue layout)
  __shared__ float bldsT[12 * 128];     // 6,144 B (k-loop layout)

  const int tid  = threadIdx.x;
  const int m0   = blockIdx.x * 128;
  const int lane = tid & 63;
  const int wid  = tid >> 6;
  const int wm   = wid >> 2;
  const int wn   = wid & 3;
  const int q    = lane >> 4;
  const int l16  = lane & 15;

  // issue layer-1 B t=0,1 first (latency hidden under feat staging)
  stage_b(Wp0,        Bl,        wid, lane);
  stage_b(Wp0 + 8192, Bl + 8192, wid, lane);

  // ---- stage features (128 x 256, f32 -> f16) into LDS ----
  #pragma unroll
  for (int it = 0; it < 16; ++it){
    int idx = it * 512 + tid;            // 8192 float4 chunks
    int m = idx >> 6, c = idx & 63;
    float4 v = *(const float4*)(feat + (size_t)(m0 + m) * 256 + c * 4);
    half4 h = { (_Float16)v.x, (_Float16)v.y, (_Float16)v.z, (_Float16)v.w };
    *(half4*)&Xl[m * XPAD + c * 4] = h;
  }
  if (tid < 128){
    float t = treat[m0 + tid];
    float p[12]; make_basis(t, p);
    const int r   = tid;
    const int tmt = (r >> 4) & 3;
    const int tl  = r & 15;
    const int twm = r >> 6;
    #pragma unroll
    for (int s = 0; s < 12; ++s){
      blds [s * 128 + r] = p[s];
      bldsT[s * 128 + twm * 64 + tl * 4 + tmt] = p[s];
    }
  }
  __syncthreads();   // drains vmcnt(0): slots 0,1 landed

  const unsigned xbase = (unsigned)(wm * 64 + l16) * XPAD + q * 8;

  const floatx4 zero = {0.f, 0.f, 0.f, 0.f};
  floatx4 acc[4][4];
  #pragma unroll
  for (int mt = 0; mt < 4; ++mt)
    #pragma unroll
    for (int nt = 0; nt < 4; ++nt) acc[mt][nt] = zero;

  // ---- layer 1 ----
  gemm_kloop(Xl, Bl, bldsT, Wp0, xbase, wm, wn, l16, wid, lane, acc);
  add_bias(blds, b0, wm, wn, q, l16, acc);
  __syncthreads();                       // also drains the 2 tail pad-loads
  scatter_to_xl(Xl, acc, wm, wn, q, l16);
  // issue layer-2 B t=0,1 under the barrier + A-read shadow
  stage_b(Wp1,        Bl,        wid, lane);
  stage_b(Wp1 + 8192, Bl + 8192, wid, lane);
  __syncthreads();                       // Xl rewritten + slots 0,1 landed

  // ---- layer 2 ----
  #pragma unroll
  for (int mt = 0; mt < 4; ++mt)
    #pragma unroll
    for (int nt = 0; nt < 4; ++nt) acc[mt][nt] = zero;
  gemm_kloop(Xl, Bl, bldsT, Wp1, xbase, wm, wn, l16, wid, lane, acc);
  add_bias(blds, b1, wm, wn, q, l16, acc);

  // ---- X2 store: bounce through Xl, then coalesced half8 lines ----
  __syncthreads();                       // all waves done reading Xl (L2 GEMM)
  scatter_to_xl(Xl, acc, wm, wn, q, l16);
  __syncthreads();
  #pragma unroll
  for (int it = 0; it < 8; ++it){
    int idx = it * 512 + tid;            // 4096 half8 chunks
    int m = idx >> 5, c = idx & 31;
    half8 v = *(const half8*)&Xl[m * XPAD + c * 8];
    *(half8*)(X2 + (size_t)(m0 + m) * 256 + c * 8) = v;
  }
}

// Final layer (out dim 1): one wave per 4 rows, W2 staged in LDS. 2048 blocks.
__global__ __launch_bounds__(256)
void final_kernel(const _Float16* __restrict__ X2, const float* __restrict__ treat,
                  const float* __restrict__ W2, const float* __restrict__ b2,
                  float* __restrict__ out){
  __shared__ float w2l[12 * 256];
  __shared__ float b2l[12];
  const int tid = threadIdx.x;
  const int m0 = blockIdx.x * 16;
  #pragma unroll
  for (int it = 0; it < 12; ++it) w2l[it * 256 + tid] = W2[it * 256 + tid];
  if (tid < 12) b2l[tid] = b2[tid];
  __syncthreads();
  const int lane = tid & 63, wid = tid >> 6;
  #pragma unroll
  for (int rr = 0; rr < 4; ++rr){
    int b = m0 + wid * 4 + rr;
    float t = treat[b];
    float p[12]; make_basis(t, p);
    half4 xv = *(const half4*)(X2 + (size_t)b * 256 + lane * 4);
    float xs[4] = { (float)xv.x, (float)xv.y, (float)xv.z, (float)xv.w };
    float ws[4] = {0.f, 0.f, 0.f, 0.f};
    #pragma unroll
    for (int s = 0; s < 12; ++s){
      floatx4 w4 = *(const floatx4*)&w2l[s * 256 + lane * 4];
      #pragma unroll
      for (int j = 0; j < 4; ++j) ws[j] += p[s] * w4[j];
    }
    float dot = xs[0]*ws[0] + xs[1]*ws[1] + xs[2]*ws[2] + xs[3]*ws[3];
    #pragma unroll
    for (int off = 32; off > 0; off >>= 1) dot += __shfl_down(dot, off, 64);
    if (lane == 0){
      float bb = 0.f;
      #pragma unroll
      for (int s = 0; s < 12; ++s) bb += p[s] * b2l[s];
      out[b] = dot + bb;
    }
  }
}

extern "C" void kernel_launch(void* const* d_in, const int* in_sizes, int n_in,
                              void* d_out, int out_size, void* d_ws, size_t ws_size,
                              hipStream_t stream){
  const float* treat = (const float*)d_in[0];
  const float* feat  = (const float*)d_in[1];
  const float* W0    = (const float*)d_in[2];
  const float* b0    = (const float*)d_in[3];
  const float* W1    = (const float*)d_in[4];
  const float* b1    = (const float*)d_in[5];
  const float* W2    = (const float*)d_in[6];
  const float* b2    = (const float*)d_in[7];

  char* ws = (char*)d_ws;
  _Float16* Wp0 = (_Float16*)(ws);                     // 1,572,864 B
  _Float16* Wp1 = (_Float16*)(ws + 1572864);           // 1,572,864 B (Wp0 overrun pad)
  _Float16* X2  = (_Float16*)(ws + 3145728);           // 16,777,216 B (Wp1 overrun pad)
  float* out = (float*)d_out;

  pack_w_kernel<<<192, 256, 0, stream>>>(W0, W1, Wp0, Wp1);
  fused_layers_kernel<<<256, 512, 0, stream>>>(feat, treat, Wp0, b0, Wp1, b1, X2);
  final_kernel<<<2048, 256, 0, stream>>>(X2, treat, W2, b2, out);
}

// Round 7
// 186.135 us; speedup vs baseline: 2.1696x; 1.0254x over previous
//
#include <hip/hip_runtime.h>

// DynamicHead R7 = R6 + register double-buffer on the B path (T3/T4 complete).
// R6 counters: fused 135us, MfmaUtil 31%, FETCH 29MB (L2 dedup works), kstep
// = 1688 cyc vs 620 cyc MFMA floor -> serial barrier->ds_read->MFMA chain.
// Fix: read kstep t+1's B-frags into regs during kstep t's MFMA phase; MFMAs
// issue from registers right after the barrier; ds_reads + stage-issue retire
// under the MFMA shadow. vmcnt ledger: vmcnt(2), reads one slot ahead.

typedef __attribute__((ext_vector_type(8))) _Float16 half8;
typedef __attribute__((ext_vector_type(4))) _Float16 half4;
typedef __attribute__((ext_vector_type(4))) float floatx4;

#define XPAD 264  // halves per LDS row: 256 + 8

__device__ __forceinline__ void gload16(const _Float16* g, _Float16* l){
  // async global->LDS, 16B/lane; LDS dest = wave-uniform base + lane*16
  __builtin_amdgcn_global_load_lds(
      (const __attribute__((address_space(1))) void*)g,
      (__attribute__((address_space(3))) void*)l, 16, 0, 0);
}

// Stage one 16KB kstep-block of packed W into an LDS slot (2 chunks/thread).
// Layout is linear: byte i of the block -> slot byte i (lanes consume it so).
__device__ __forceinline__ void stage_b(const _Float16* wt, _Float16* slot,
                                        int w, int l){
  gload16(wt +        w * 512 + l * 8, slot +        w * 512);
  gload16(wt + 4096 + w * 512 + l * 8, slot + 4096 + w * 512);
}

__device__ __forceinline__ void make_basis(float t, float* p){
  p[0] = 1.f; p[1] = t; p[2] = t*t; p[3] = p[2]*t;
  const float knots[8] = {1.f/9.f, 2.f/9.f, 3.f/9.f, 4.f/9.f,
                          5.f/9.f, 6.f/9.f, 7.f/9.f, 8.f/9.f};
  #pragma unroll
  for (int j = 0; j < 8; ++j){
    float d = t - knots[j];
    d = fmaxf(d, 0.f);
    p[4+j] = d*d*d;
  }
}

// Pack W (12,256,256) fp32 -> f16 MFMA-B-frag order via LDS transpose.
// kappa = s*8+ko; destination block position t = ko*12 + s (ko-outer stream
// order so the layer kernel's B pointer advances linearly 8192 halves/kstep).
__global__ __launch_bounds__(256)
void pack_w_kernel(const float* __restrict__ W0, const float* __restrict__ W1,
                   _Float16* __restrict__ Wp0, _Float16* __restrict__ Wp1){
  __shared__ float wl[32 * 260];
  const int blk = blockIdx.x;
  const float* W = (blk < 96) ? W0 : W1;
  _Float16* Wp   = (blk < 96) ? Wp0 : Wp1;
  const int c    = (blk < 96) ? blk : blk - 96;   // kappa = s*8+ko
  const int tid  = threadIdx.x;
  const float* src = W + (size_t)c * 8192;        // 32 k-rows x 256 cols
  #pragma unroll
  for (int it = 0; it < 8; ++it){
    int idx = it * 256 + tid;          // float4 index 0..2047
    int r = idx >> 6, c4 = idx & 63;
    float4 v = *(const float4*)(src + (size_t)idx * 4);
    float* d = &wl[r * 260 + c4 * 4];
    d[0] = v.x; d[1] = v.y; d[2] = v.z; d[3] = v.w;
  }
  __syncthreads();
  const int tpos = (c & 7) * 12 + (c >> 3);       // ko*12 + s
  _Float16* dst = Wp + (size_t)tpos * 8192;
  #pragma unroll
  for (int w = 0; w < 4; ++w){
    int v = w * 256 + tid;             // 0..1023
    int n16 = v & 15, qq = (v >> 4) & 3, ntg = v >> 6;
    half8 o;
    #pragma unroll
    for (int j = 0; j < 8; ++j)
      o[j] = (_Float16)wl[(qq * 8 + j) * 260 + ntg * 16 + n16];
    *(half8*)(dst + (size_t)v * 8) = o;
  }
}

// 96-kstep GEMM pass, LDS ring (4 x 16KB) + register double buffer.
// Iter t: vmcnt(2) [loads of t+1 landed; t+2's in flight] -> barrier ->
// issue ds_reads of kstep t+1 into bn -> MFMA kstep t from bc (regs only)
// -> rotate -> issue stage of t+3 (lands >=2 barriers later; WAR-safe: slot
// (t+3)&3 was last read at iter t-2, two collective barriers earlier).
// Slot/buffer indices compile-time static since 12 % 4 == 0.
// Caller pre-stages slots 0,1 + __syncthreads (drain). Prologue stages slot 2.
// Tail stages (blocks 96..98) overrun <=48KiB into the next allocated region.
__device__ __forceinline__ void gemm_kloop(const _Float16* Xl, _Float16* Bl,
                                           const float* bldsT,
                                           const _Float16* __restrict__ wp,
                                           unsigned xbase, int wm, int wn,
                                           int l16, int w, int l,
                                           floatx4 acc[4][4]){
  const unsigned bbase = (unsigned)(wn * 2048 + l * 8);   // halves within slot
  half8 xc[4], xn[4], bc[4], bn[4];
  // prologue: issue slot-2 stage, then load kstep-0 state from LDS/regs
  stage_b(wp + 2 * 8192, Bl + 2 * 8192, w, l);
  #pragma unroll
  for (int nt = 0; nt < 4; ++nt)
    bc[nt] = *(const half8*)(Bl + bbase + nt * 512);      // slot 0 = kstep 0
  #pragma unroll
  for (int mt = 0; mt < 4; ++mt)
    xc[mt] = *(const half8*)&Xl[xbase + mt * 16 * XPAD];
  floatx4 btc = *(const floatx4*)&bldsT[wm * 64 + l16 * 4]; // s = 0

  for (int ko = 0; ko < 8; ++ko){
    #pragma unroll
    for (int s = 0; s < 12; ++s){
      // loads of kstep t+1 must be retired; the 2 loads of t+2 stay in flight
      __asm__ __volatile__("s_waitcnt vmcnt(2)" ::: "memory");
      __builtin_amdgcn_sched_barrier(0);
      __builtin_amdgcn_s_barrier();   // all waves' t+1 loads landed
      __builtin_amdgcn_sched_barrier(0);

      // issue reads for kstep t+1 (retire under the MFMA block below)
      #pragma unroll
      for (int nt = 0; nt < 4; ++nt)
        bn[nt] = *(const half8*)(Bl + ((s + 1) & 3) * 8192 + bbase + nt * 512);
      const int sn = (s == 11) ? 0 : s + 1;
      floatx4 btn = *(const floatx4*)&bldsT[sn * 128 + wm * 64 + l16 * 4];
      if (s == 0){   // next ko's A-frags (needed 12 ksteps later)
        const int kon = (ko + 1) & 7;   // wraps at ko=7; result discarded
        #pragma unroll
        for (int mt = 0; mt < 4; ++mt)
          xn[mt] = *(const half8*)&Xl[xbase + kon * 32 + mt * 16 * XPAD];
      }

      // kstep t: registers only — basis scale then 16 MFMA
      _Float16 bh[4];
      #pragma unroll
      for (int mt = 0; mt < 4; ++mt) bh[mt] = (_Float16)btc[mt];
      half8 az[4];
      #pragma unroll
      for (int mt = 0; mt < 4; ++mt) az[mt] = xc[mt] * bh[mt];
      #pragma unroll
      for (int mt = 0; mt < 4; ++mt)
        #pragma unroll
        for (int nt = 0; nt < 4; ++nt)
          acc[mt][nt] = __builtin_amdgcn_mfma_f32_16x16x32_f16(
              az[mt], bc[nt], acc[mt][nt], 0, 0, 0);

      // rotate double buffers (renamed away by unroll)
      #pragma unroll
      for (int nt = 0; nt < 4; ++nt) bc[nt] = bn[nt];
      btc = btn;
      if (s == 11){
        #pragma unroll
        for (int mt = 0; mt < 4; ++mt) xc[mt] = xn[mt];
      }
      // issue stage for kstep t+3 under the MFMA shadow
      stage_b(wp + (size_t)(ko * 12 + s + 3) * 8192,
              Bl + ((s + 3) & 3) * 8192, w, l);
    }
  }
}

// acc[mt][nt] += sum_s bas_s[row] * bias[s, col]
__device__ __forceinline__ void add_bias(const float* blds, const float* __restrict__ bias,
                                         int wm, int wn, int q, int l16,
                                         floatx4 acc[4][4]){
  for (int s = 0; s < 12; ++s){
    float bl[4];
    #pragma unroll
    for (int nt = 0; nt < 4; ++nt)
      bl[nt] = bias[s * 256 + wn * 64 + nt * 16 + l16];
    floatx4 bs[4];
    #pragma unroll
    for (int mt = 0; mt < 4; ++mt)
      bs[mt] = *(const floatx4*)&blds[s * 128 + wm * 64 + mt * 16 + q * 4];
    #pragma unroll
    for (int mt = 0; mt < 4; ++mt)
      #pragma unroll
      for (int nt = 0; nt < 4; ++nt)
        #pragma unroll
        for (int r = 0; r < 4; ++r)
          acc[mt][nt][r] += bs[mt][r] * bl[nt];
  }
}

// relu + scatter acc into Xl as f16 (C/D layout: col=lane&15, row=(lane>>4)*4+r)
__device__ __forceinline__ void scatter_to_xl(_Float16* Xl, floatx4 acc[4][4],
                                              int wm, int wn, int q, int l16){
  #pragma unroll
  for (int mt = 0; mt < 4; ++mt)
    #pragma unroll
    for (int nt = 0; nt < 4; ++nt)
      #pragma unroll
      for (int r = 0; r < 4; ++r)
        Xl[(wm * 64 + mt * 16 + q * 4 + r) * XPAD + wn * 64 + nt * 16 + l16] =
            (_Float16)fmaxf(acc[mt][nt][r], 0.f);
}

// Fused layers 1+2: 128 rows x 256 cols per block, 512 thr = 8 waves (2m x 4n).
// Grid 256 -> 1 block/CU. LDS: Xl 67.5K + Bl 64K + basis 12K = 145,408 B.
__global__ __launch_bounds__(512, 2)
void fused_layers_kernel(const float* __restrict__ feat, const float* __restrict__ treat,
                         const _Float16* __restrict__ Wp0, const float* __restrict__ b0,
                         const _Float16* __restrict__ Wp1, const float* __restrict__ b1,
                         _Float16* __restrict__ X2){
  __shared__ _Float16 Xl[128 * XPAD];   // 67,584 B
  __shared__ _Float16 Bl[4 * 8192];     // 65,536 B (B ring)
  __shared__ float blds[12 * 128];      // 6,144 B (epilogue layout)
  __shared__ float bldsT[12 * 128];     // 6,144 B (k-loop layout)

  const int tid  = threadIdx.x;
  const int m0   = blockIdx.x * 128;
  const int lane = tid & 63;
  const int wid  = tid >> 6;
  const int wm   = wid >> 2;
  const int wn   = wid & 3;
  const int q    = lane >> 4;
  const int l16  = lane & 15;

  // issue layer-1 B t=0,1 first (latency hidden under feat staging)
  stage_b(Wp0,        Bl,        wid, lane);
  stage_b(Wp0 + 8192, Bl + 8192, wid, lane);

  // ---- stage features (128 x 256, f32 -> f16) into LDS ----
  #pragma unroll
  for (int it = 0; it < 16; ++it){
    int idx = it * 512 + tid;            // 8192 float4 chunks
    int m = idx >> 6, c = idx & 63;
    float4 v = *(const float4*)(feat + (size_t)(m0 + m) * 256 + c * 4);
    half4 h = { (_Float16)v.x, (_Float16)v.y, (_Float16)v.z, (_Float16)v.w };
    *(half4*)&Xl[m * XPAD + c * 4] = h;
  }
  if (tid < 128){
    float t = treat[m0 + tid];
    float p[12]; make_basis(t, p);
    const int r   = tid;
    const int tmt = (r >> 4) & 3;
    const int tl  = r & 15;
    const int twm = r >> 6;
    #pragma unroll
    for (int s = 0; s < 12; ++s){
      blds [s * 128 + r] = p[s];
      bldsT[s * 128 + twm * 64 + tl * 4 + tmt] = p[s];
    }
  }
  __syncthreads();   // drains vmcnt(0): slots 0,1 landed

  const unsigned xbase = (unsigned)(wm * 64 + l16) * XPAD + q * 8;

  const floatx4 zero = {0.f, 0.f, 0.f, 0.f};
  floatx4 acc[4][4];
  #pragma unroll
  for (int mt = 0; mt < 4; ++mt)
    #pragma unroll
    for (int nt = 0; nt < 4; ++nt) acc[mt][nt] = zero;

  // ---- layer 1 ----
  gemm_kloop(Xl, Bl, bldsT, Wp0, xbase, wm, wn, l16, wid, lane, acc);
  add_bias(blds, b0, wm, wn, q, l16, acc);
  __syncthreads();                       // drains the tail pad-loads
  scatter_to_xl(Xl, acc, wm, wn, q, l16);
  // issue layer-2 B t=0,1 under the barrier + scatter shadow
  stage_b(Wp1,        Bl,        wid, lane);
  stage_b(Wp1 + 8192, Bl + 8192, wid, lane);
  __syncthreads();                       // Xl rewritten + slots 0,1 landed

  // ---- layer 2 ----
  #pragma unroll
  for (int mt = 0; mt < 4; ++mt)
    #pragma unroll
    for (int nt = 0; nt < 4; ++nt) acc[mt][nt] = zero;
  gemm_kloop(Xl, Bl, bldsT, Wp1, xbase, wm, wn, l16, wid, lane, acc);
  add_bias(blds, b1, wm, wn, q, l16, acc);

  // ---- X2 store: bounce through Xl, then coalesced half8 lines ----
  __syncthreads();                       // all waves done reading Xl (L2 GEMM)
  scatter_to_xl(Xl, acc, wm, wn, q, l16);
  __syncthreads();
  #pragma unroll
  for (int it = 0; it < 8; ++it){
    int idx = it * 512 + tid;            // 4096 half8 chunks
    int m = idx >> 5, c = idx & 31;
    half8 v = *(const half8*)&Xl[m * XPAD + c * 8];
    *(half8*)(X2 + (size_t)(m0 + m) * 256 + c * 8) = v;
  }
}

// Final layer (out dim 1): one wave per 4 rows, W2 staged in LDS. 2048 blocks.
__global__ __launch_bounds__(256)
void final_kernel(const _Float16* __restrict__ X2, const float* __restrict__ treat,
                  const float* __restrict__ W2, const float* __restrict__ b2,
                  float* __restrict__ out){
  __shared__ float w2l[12 * 256];
  __shared__ float b2l[12];
  const int tid = threadIdx.x;
  const int m0 = blockIdx.x * 16;
  #pragma unroll
  for (int it = 0; it < 12; ++it) w2l[it * 256 + tid] = W2[it * 256 + tid];
  if (tid < 12) b2l[tid] = b2[tid];
  __syncthreads();
  const int lane = tid & 63, wid = tid >> 6;
  #pragma unroll
  for (int rr = 0; rr < 4; ++rr){
    int b = m0 + wid * 4 + rr;
    float t = treat[b];
    float p[12]; make_basis(t, p);
    half4 xv = *(const half4*)(X2 + (size_t)b * 256 + lane * 4);
    float xs[4] = { (float)xv.x, (float)xv.y, (float)xv.z, (float)xv.w };
    float ws[4] = {0.f, 0.f, 0.f, 0.f};
    #pragma unroll
    for (int s = 0; s < 12; ++s){
      floatx4 w4 = *(const floatx4*)&w2l[s * 256 + lane * 4];
      #pragma unroll
      for (int j = 0; j < 4; ++j) ws[j] += p[s] * w4[j];
    }
    float dot = xs[0]*ws[0] + xs[1]*ws[1] + xs[2]*ws[2] + xs[3]*ws[3];
    #pragma unroll
    for (int off = 32; off > 0; off >>= 1) dot += __shfl_down(dot, off, 64);
    if (lane == 0){
      float bb = 0.f;
      #pragma unroll
      for (int s = 0; s < 12; ++s) bb += p[s] * b2l[s];
      out[b] = dot + bb;
    }
  }
}

extern "C" void kernel_launch(void* const* d_in, const int* in_sizes, int n_in,
                              void* d_out, int out_size, void* d_ws, size_t ws_size,
                              hipStream_t stream){
  const float* treat = (const float*)d_in[0];
  const float* feat  = (const float*)d_in[1];
  const float* W0    = (const float*)d_in[2];
  const float* b0    = (const float*)d_in[3];
  const float* W1    = (const float*)d_in[4];
  const float* b1    = (const float*)d_in[5];
  const float* W2    = (const float*)d_in[6];
  const float* b2    = (const float*)d_in[7];

  char* ws = (char*)d_ws;
  _Float16* Wp0 = (_Float16*)(ws);                     // 1,572,864 B
  _Float16* Wp1 = (_Float16*)(ws + 1572864);           // 1,572,864 B (Wp0 overrun pad)
  _Float16* X2  = (_Float16*)(ws + 3145728);           // 16,777,216 B (Wp1 overrun pad)
  float* out = (float*)d_out;

  pack_w_kernel<<<192, 256, 0, stream>>>(W0, W1, Wp0, Wp1);
  fused_layers_kernel<<<256, 512, 0, stream>>>(feat, treat, Wp0, b0, Wp1, b1, X2);
  final_kernel<<<2048, 256, 0, stream>>>(X2, treat, W2, b2, out);
}